// Round 3
// baseline (560.240 us; speedup 1.0000x reference)
//
#include <hip/hip_runtime.h>

#define N_NODES 100000
#define F_IN 128
#define H 16
#define NBIN 391           // ceil(N_NODES / 256); bin b owns nodes [b*256, b*256+256)
#define BINCAP 4608        // per-bin record capacity (mean 4096, +8 sigma)
#define ECHUNK 4096        // edges per binfill block

// ---------------------------------------------------------------------------
// k_init: binCur[b] = b * BINCAP  (record-region cursors)
// ---------------------------------------------------------------------------
__global__ void __launch_bounds__(512) k_init(int* __restrict__ binCur) {
  int t = threadIdx.x;
  if (t < NBIN) binCur[t] = t * BINCAP;
}

// ---------------------------------------------------------------------------
// k_lin1: y1l = x @ W1l, y1r = x @ W1r  (thread per node)
// ---------------------------------------------------------------------------
__global__ void __launch_bounds__(256) k_lin1(
    const float* __restrict__ x, const float* __restrict__ W1l,
    const float* __restrict__ W1r, float* __restrict__ y1l,
    float* __restrict__ y1r) {
  int n = blockIdx.x * 256 + threadIdx.x;
  if (n >= N_NODES) return;
  const float4* xr = (const float4*)(x + (size_t)n * F_IN);
  float al[H], ar[H];
#pragma unroll
  for (int c = 0; c < H; ++c) { al[c] = 0.f; ar[c] = 0.f; }
  float4 xv = xr[0];
  for (int k4 = 0; k4 < F_IN / 4; ++k4) {
    float4 cur = xv;
    if (k4 + 1 < F_IN / 4) xv = xr[k4 + 1];
    float xs[4] = {cur.x, cur.y, cur.z, cur.w};
#pragma unroll
    for (int j = 0; j < 4; ++j) {
      int k = k4 * 4 + j;
#pragma unroll
      for (int c = 0; c < H; ++c) {
        al[c] = fmaf(xs[j], W1l[k * H + c], al[c]);
        ar[c] = fmaf(xs[j], W1r[k * H + c], ar[c]);
      }
    }
  }
  float4* ol = (float4*)(y1l + (size_t)n * H);
  float4* orr = (float4*)(y1r + (size_t)n * H);
#pragma unroll
  for (int q = 0; q < 4; ++q) {
    ol[q] = make_float4(al[4 * q], al[4 * q + 1], al[4 * q + 2], al[4 * q + 3]);
    orr[q] = make_float4(ar[4 * q], ar[4 * q + 1], ar[4 * q + 2], ar[4 * q + 3]);
  }
}

// ---------------------------------------------------------------------------
// k_binfill: bin records (src<<8 | dstLow) by dst>>8. Per-block LDS histogram,
// one global cursor atomicAdd per (block,bin), then ranged writes (~2 blocks
// per 64B line instead of ~16 random writers -> low write amplification).
// ---------------------------------------------------------------------------
__global__ void __launch_bounds__(512) k_binfill(
    const int* __restrict__ src, const int* __restrict__ dst,
    int* __restrict__ binCur, int* __restrict__ recs, int E) {
  __shared__ int hist[512];
  __shared__ int gbase[512];
  __shared__ int cnt2[512];
  int t = threadIdx.x;
  hist[t] = 0;
  cnt2[t] = 0;
  __syncthreads();
  int base = blockIdx.x * ECHUNK;
  int rec[8], bin[8];
#pragma unroll
  for (int j = 0; j < 8; ++j) {
    int e = base + j * 512 + t;
    if (e < E) {
      int s = src[e];
      int d = dst[e];
      rec[j] = (s << 8) | (d & 255);
      bin[j] = d >> 8;
      atomicAdd(&hist[bin[j]], 1);
    } else {
      bin[j] = -1;
    }
  }
  __syncthreads();
  if (t < NBIN) {
    int c = hist[t];
    gbase[t] = (c > 0) ? atomicAdd(&binCur[t], c) : 0;
  }
  __syncthreads();
#pragma unroll
  for (int j = 0; j < 8; ++j) {
    if (bin[j] >= 0) {
      int loc = atomicAdd(&cnt2[bin[j]], 1);
      int slot = gbase[bin[j]] + loc;
      if (slot < (bin[j] + 1) * BINCAP)  // safety clamp (never expected)
        recs[slot] = rec[j];
    }
  }
}

// ---------------------------------------------------------------------------
// k_bagg1: per-bin aggregation of y1l rows into LDS (ds_add_f32), degree
// count in LDS, then fused combine1: h1 = relu(mean + b1 + y1r);
// z2l = h1@W2l, z2r = h1@W2r (W2 staged in LDS). 1024 threads = 16 waves,
// 64 records in flight per block.
// ---------------------------------------------------------------------------
__global__ void __launch_bounds__(1024) k_bagg1(
    const int* __restrict__ recs, const int* __restrict__ binCur,
    const float* __restrict__ y1l, const float* __restrict__ y1r,
    const float* __restrict__ b1, const float* __restrict__ W2l,
    const float* __restrict__ W2r, float* __restrict__ z2l,
    float* __restrict__ z2r) {
  __shared__ float acc[256 * H];
  __shared__ int scnt[256];
  __shared__ float w2[2 * 256];
  int t = threadIdx.x;
  int b = blockIdx.x;
#pragma unroll
  for (int j = 0; j < 4; ++j) acc[j * 1024 + t] = 0.f;
  if (t < 256) {
    scnt[t] = 0;
    w2[t] = W2l[t];
    w2[256 + t] = W2r[t];
  }
  __syncthreads();
  int rbase = b * BINCAP;
  int R = binCur[b] - rbase;
  if (R > BINCAP) R = BINCAP;
  int g = t >> 4;      // record group 0..63
  int c = t & 15;      // channel
  int i = g;
  for (; i + 192 < R; i += 256) {
    int r0 = recs[rbase + i];
    int r1 = recs[rbase + i + 64];
    int r2 = recs[rbase + i + 128];
    int r3 = recs[rbase + i + 192];
    float v0 = y1l[(size_t)(r0 >> 8) * H + c];
    float v1 = y1l[(size_t)(r1 >> 8) * H + c];
    float v2 = y1l[(size_t)(r2 >> 8) * H + c];
    float v3 = y1l[(size_t)(r3 >> 8) * H + c];
    atomicAdd(&acc[(r0 & 255) * H + c], v0);
    atomicAdd(&acc[(r1 & 255) * H + c], v1);
    atomicAdd(&acc[(r2 & 255) * H + c], v2);
    atomicAdd(&acc[(r3 & 255) * H + c], v3);
    if (c == 0) {
      atomicAdd(&scnt[r0 & 255], 1);
      atomicAdd(&scnt[r1 & 255], 1);
      atomicAdd(&scnt[r2 & 255], 1);
      atomicAdd(&scnt[r3 & 255], 1);
    }
  }
  for (; i < R; i += 64) {
    int r0 = recs[rbase + i];
    float v0 = y1l[(size_t)(r0 >> 8) * H + c];
    atomicAdd(&acc[(r0 & 255) * H + c], v0);
    if (c == 0) atomicAdd(&scnt[r0 & 255], 1);
  }
  __syncthreads();
  if (t < 256) {
    int n = (b << 8) + t;
    if (n < N_NODES) {
      float inv = 1.f / fmaxf((float)scnt[t], 1.f);
      const float4* yr = (const float4*)(y1r + (size_t)n * H);
      float h1[H];
#pragma unroll
      for (int q = 0; q < 4; ++q) {
        float4 y = yr[q];
        h1[4 * q + 0] = fmaxf(fmaf(acc[t * H + 4 * q + 0], inv, b1[4 * q + 0] + y.x), 0.f);
        h1[4 * q + 1] = fmaxf(fmaf(acc[t * H + 4 * q + 1], inv, b1[4 * q + 1] + y.y), 0.f);
        h1[4 * q + 2] = fmaxf(fmaf(acc[t * H + 4 * q + 2], inv, b1[4 * q + 2] + y.z), 0.f);
        h1[4 * q + 3] = fmaxf(fmaf(acc[t * H + 4 * q + 3], inv, b1[4 * q + 3] + y.w), 0.f);
      }
      float zl[H], zr[H];
#pragma unroll
      for (int cc = 0; cc < H; ++cc) { zl[cc] = 0.f; zr[cc] = 0.f; }
#pragma unroll
      for (int k = 0; k < H; ++k) {
        float hk = h1[k];
#pragma unroll
        for (int cc = 0; cc < H; ++cc) {
          zl[cc] = fmaf(hk, w2[k * H + cc], zl[cc]);
          zr[cc] = fmaf(hk, w2[256 + k * H + cc], zr[cc]);
        }
      }
      float4* outl = (float4*)(z2l + (size_t)n * H);
      float4* outr = (float4*)(z2r + (size_t)n * H);
#pragma unroll
      for (int q = 0; q < 4; ++q) {
        outl[q] = make_float4(zl[4 * q], zl[4 * q + 1], zl[4 * q + 2], zl[4 * q + 3]);
        outr[q] = make_float4(zr[4 * q], zr[4 * q + 1], zr[4 * q + 2], zr[4 * q + 3]);
      }
    }
  }
}

// ---------------------------------------------------------------------------
// k_bagg2: same aggregation over z2l, fused combine2: h2 = mean + b2 + z2r
// ---------------------------------------------------------------------------
__global__ void __launch_bounds__(1024) k_bagg2(
    const int* __restrict__ recs, const int* __restrict__ binCur,
    const float* __restrict__ z2l, const float* __restrict__ z2r,
    const float* __restrict__ b2, float* __restrict__ h2) {
  __shared__ float acc[256 * H];
  __shared__ int scnt[256];
  int t = threadIdx.x;
  int b = blockIdx.x;
#pragma unroll
  for (int j = 0; j < 4; ++j) acc[j * 1024 + t] = 0.f;
  if (t < 256) scnt[t] = 0;
  __syncthreads();
  int rbase = b * BINCAP;
  int R = binCur[b] - rbase;
  if (R > BINCAP) R = BINCAP;
  int g = t >> 4;
  int c = t & 15;
  int i = g;
  for (; i + 192 < R; i += 256) {
    int r0 = recs[rbase + i];
    int r1 = recs[rbase + i + 64];
    int r2 = recs[rbase + i + 128];
    int r3 = recs[rbase + i + 192];
    float v0 = z2l[(size_t)(r0 >> 8) * H + c];
    float v1 = z2l[(size_t)(r1 >> 8) * H + c];
    float v2 = z2l[(size_t)(r2 >> 8) * H + c];
    float v3 = z2l[(size_t)(r3 >> 8) * H + c];
    atomicAdd(&acc[(r0 & 255) * H + c], v0);
    atomicAdd(&acc[(r1 & 255) * H + c], v1);
    atomicAdd(&acc[(r2 & 255) * H + c], v2);
    atomicAdd(&acc[(r3 & 255) * H + c], v3);
    if (c == 0) {
      atomicAdd(&scnt[r0 & 255], 1);
      atomicAdd(&scnt[r1 & 255], 1);
      atomicAdd(&scnt[r2 & 255], 1);
      atomicAdd(&scnt[r3 & 255], 1);
    }
  }
  for (; i < R; i += 64) {
    int r0 = recs[rbase + i];
    float v0 = z2l[(size_t)(r0 >> 8) * H + c];
    atomicAdd(&acc[(r0 & 255) * H + c], v0);
    if (c == 0) atomicAdd(&scnt[r0 & 255], 1);
  }
  __syncthreads();
  if (t < 256) {
    int n = (b << 8) + t;
    if (n < N_NODES) {
      float inv = 1.f / fmaxf((float)scnt[t], 1.f);
      const float4* zr = (const float4*)(z2r + (size_t)n * H);
      float4* out = (float4*)(h2 + (size_t)n * H);
#pragma unroll
      for (int q = 0; q < 4; ++q) {
        float4 z = zr[q];
        float4 o;
        o.x = fmaf(acc[t * H + 4 * q + 0], inv, b2[4 * q + 0] + z.x);
        o.y = fmaf(acc[t * H + 4 * q + 1], inv, b2[4 * q + 1] + z.y);
        o.z = fmaf(acc[t * H + 4 * q + 2], inv, b2[4 * q + 2] + z.z);
        o.w = fmaf(acc[t * H + 4 * q + 3], inv, b2[4 * q + 3] + z.w);
        out[q] = o;
      }
    }
  }
}

// ---------------------------------------------------------------------------
// decode: out[p] = sigmoid(dot(h2[s], h2[d]))
// ---------------------------------------------------------------------------
__global__ void __launch_bounds__(256) k_decode(
    const int* __restrict__ ps, const int* __restrict__ pd,
    const float* __restrict__ h2, float* __restrict__ out, int P) {
  int p = blockIdx.x * 256 + threadIdx.x;
  if (p >= P) return;
  int a = ps[p];
  int b = pd[p];
  const float4* ha = (const float4*)(h2 + (size_t)a * H);
  const float4* hb = (const float4*)(h2 + (size_t)b * H);
  float acc = 0.f;
#pragma unroll
  for (int q = 0; q < 4; ++q) {
    float4 u = ha[q];
    float4 v = hb[q];
    acc = fmaf(u.x, v.x, acc);
    acc = fmaf(u.y, v.y, acc);
    acc = fmaf(u.z, v.z, acc);
    acc = fmaf(u.w, v.w, acc);
  }
  out[p] = 1.f / (1.f + __expf(-acc));
}

// ---------------------------------------------------------------------------
extern "C" void kernel_launch(void* const* d_in, const int* in_sizes, int n_in,
                              void* d_out, int out_size, void* d_ws, size_t ws_size,
                              hipStream_t stream) {
  const float* x   = (const float*)d_in[0];
  const float* W1l = (const float*)d_in[1];
  const float* b1  = (const float*)d_in[2];
  const float* W1r = (const float*)d_in[3];
  const float* W2l = (const float*)d_in[4];
  const float* b2  = (const float*)d_in[5];
  const float* W2r = (const float*)d_in[6];
  const int* ei = (const int*)d_in[7];  // [2, E] int32
  const int* di = (const int*)d_in[8];  // [2, P] int32
  const int E = in_sizes[7] / 2;
  const int P = in_sizes[8] / 2;

  const size_t NF = (size_t)N_NODES * H;
  // Aliasing: bufA = y1l -> h2 (y1l dead after k_bagg1's record phase);
  //           bufB = y1r -> z2r (each thread reads y1r[n] for its own node
  //           only, within the same kernel+thread that writes z2r[n]).
  float* y1l = (float*)d_ws;            // NF
  float* y1r = y1l + NF;                // NF
  float* z2l = y1r + NF;                // NF
  float* z2r = y1r;                     // alias
  float* h2  = y1l;                     // alias
  int* recs   = (int*)(z2l + NF);       // NBIN * BINCAP
  int* binCur = recs + (size_t)NBIN * BINCAP;  // NBIN

  const int nodeBlocks = (N_NODES + 255) / 256;
  const int fillBlocks = (E + ECHUNK - 1) / ECHUNK;

  k_init<<<1, 512, 0, stream>>>(binCur);
  k_lin1<<<nodeBlocks, 256, 0, stream>>>(x, W1l, W1r, y1l, y1r);
  k_binfill<<<fillBlocks, 512, 0, stream>>>(ei, ei + E, binCur, recs, E);
  k_bagg1<<<NBIN, 1024, 0, stream>>>(recs, binCur, y1l, y1r, b1, W2l, W2r,
                                     z2l, z2r);
  k_bagg2<<<NBIN, 1024, 0, stream>>>(recs, binCur, z2l, z2r, b2, h2);
  k_decode<<<(P + 255) / 256, 256, 0, stream>>>(di, di + P, h2, (float*)d_out, P);
}

// Round 5
// 294.171 us; speedup vs baseline: 1.9045x; 1.9045x over previous
//
#include <hip/hip_runtime.h>

#define N_NODES 100000
#define F_IN 128
#define H 16
#define NBIN 391           // ceil(N_NODES/256); bin b owns nodes [b*256, b*256+256)
#define BINCAP 4608        // per-bin record capacity (mean 4096, +8 sigma)
#define ECHUNK 4096        // edges per binfill block

// ---------------------------------------------------------------------------
// k_init: binCur[b] = b * BINCAP  (record-region cursors)
// ---------------------------------------------------------------------------
__global__ void __launch_bounds__(512) k_init(int* __restrict__ binCur) {
  int t = threadIdx.x;
  if (t < NBIN) binCur[t] = t * BINCAP;
}

// ---------------------------------------------------------------------------
// k_lin1: y1l = x @ W1l, y1r = x @ W1r  (thread per node)
// ---------------------------------------------------------------------------
__global__ void __launch_bounds__(256) k_lin1(
    const float* __restrict__ x, const float* __restrict__ W1l,
    const float* __restrict__ W1r, float* __restrict__ y1l,
    float* __restrict__ y1r) {
  int n = blockIdx.x * 256 + threadIdx.x;
  if (n >= N_NODES) return;
  const float4* xr = (const float4*)(x + (size_t)n * F_IN);
  float al[H], ar[H];
#pragma unroll
  for (int c = 0; c < H; ++c) { al[c] = 0.f; ar[c] = 0.f; }
  float4 xv = xr[0];
  for (int k4 = 0; k4 < F_IN / 4; ++k4) {
    float4 cur = xv;
    if (k4 + 1 < F_IN / 4) xv = xr[k4 + 1];
    float xs[4] = {cur.x, cur.y, cur.z, cur.w};
#pragma unroll
    for (int j = 0; j < 4; ++j) {
      int k = k4 * 4 + j;
#pragma unroll
      for (int c = 0; c < H; ++c) {
        al[c] = fmaf(xs[j], W1l[k * H + c], al[c]);
        ar[c] = fmaf(xs[j], W1r[k * H + c], ar[c]);
      }
    }
  }
  float4* ol = (float4*)(y1l + (size_t)n * H);
  float4* orr = (float4*)(y1r + (size_t)n * H);
#pragma unroll
  for (int q = 0; q < 4; ++q) {
    ol[q] = make_float4(al[4 * q], al[4 * q + 1], al[4 * q + 2], al[4 * q + 3]);
    orr[q] = make_float4(ar[4 * q], ar[4 * q + 1], ar[4 * q + 2], ar[4 * q + 3]);
  }
}

// ---------------------------------------------------------------------------
// k_binfill: radix pass 1 — bin records (src<<8 | dstLow) by dst>>8.
// Per-block LDS histogram, one global cursor atomicAdd per (block,bin),
// then ranged (sequential) writes: ~2 writers per 64B line, low write amp.
// Record ORDER in a bin is nondeterministic (atomic races) but the record
// SET is deterministic; k_binsort canonicalizes the order.
// ---------------------------------------------------------------------------
__global__ void __launch_bounds__(512) k_binfill(
    const int* __restrict__ src, const int* __restrict__ dst,
    int* __restrict__ binCur, int* __restrict__ recs, int E) {
  __shared__ int hist[512];
  __shared__ int gbase[512];
  __shared__ int cnt2[512];
  int t = threadIdx.x;
  hist[t] = 0;
  cnt2[t] = 0;
  __syncthreads();
  int base = blockIdx.x * ECHUNK;
  int rec[8], bin[8];
#pragma unroll
  for (int j = 0; j < 8; ++j) {
    int e = base + j * 512 + t;
    if (e < E) {
      int s = src[e];
      int d = dst[e];
      rec[j] = (s << 8) | (d & 255);
      bin[j] = d >> 8;
      atomicAdd(&hist[bin[j]], 1);
    } else {
      bin[j] = -1;
    }
  }
  __syncthreads();
  if (t < NBIN) {
    int c = hist[t];
    gbase[t] = (c > 0) ? atomicAdd(&binCur[t], c) : 0;
  }
  __syncthreads();
#pragma unroll
  for (int j = 0; j < 8; ++j) {
    if (bin[j] >= 0) {
      int loc = atomicAdd(&cnt2[bin[j]], 1);
      int slot = gbase[bin[j]] + loc;
      if (slot < (bin[j] + 1) * BINCAP)  // safety clamp (never expected)
        recs[slot] = rec[j];
    }
  }
}

// ---------------------------------------------------------------------------
// k_binsort: radix pass 2 — one block per bin.
//  1) load records to LDS + histogram dstLow
//  2) scan -> per-node offsets; emit deg/rowBeg (coalesced)
//  3) group records by node into srtg (atomic order, nondeterministic)
//  4) CANONICAL rank-sort within each row: slot = #(smaller) + #(equal with
//     lower idx). Ties are equal values, so the final array is independent
//     of the grouping order -> pipeline output is bitwise deterministic.
//  5) write sorted src ids back to recs (coalesced)
// ---------------------------------------------------------------------------
__global__ void __launch_bounds__(512) k_binsort(
    int* __restrict__ recs, const int* __restrict__ binCur,
    int* __restrict__ deg, int* __restrict__ rowBeg) {
  __shared__ int lrec[BINCAP];   // raw records, reused for final sorted output
  __shared__ int srtg[BINCAP];   // node-grouped records
  __shared__ int hist[256];
  __shared__ int off[256];       // inclusive scan; (off - hist) = exclusive
  __shared__ int cur[256];
  int t = threadIdx.x;
  int b = blockIdx.x;
  int rbase = b * BINCAP;
  int R = binCur[b] - rbase;
  if (R > BINCAP) R = BINCAP;
  if (t < 256) hist[t] = 0;
  __syncthreads();
  // load + histogram
#pragma unroll
  for (int j = 0; j < 9; ++j) {
    int idx = j * 512 + t;
    if (idx < R) {
      int r = recs[rbase + idx];
      lrec[idx] = r;
      atomicAdd(&hist[r & 255], 1);
    }
  }
  __syncthreads();
  if (t < 256) off[t] = hist[t];
  __syncthreads();
  for (int o = 1; o < 256; o <<= 1) {
    int u = 0;
    if (t < 256 && t >= o) u = off[t - o];
    __syncthreads();
    if (t < 256) off[t] += u;
    __syncthreads();
  }
  if (t < 256) {
    int ex = off[t] - hist[t];
    cur[t] = ex;
    int n = (b << 8) + t;
    if (n < N_NODES) {
      deg[n] = hist[t];
      rowBeg[n] = rbase + ex;
    }
  }
  __syncthreads();
  // group by node (order within row arbitrary here)
#pragma unroll
  for (int j = 0; j < 9; ++j) {
    int idx = j * 512 + t;
    if (idx < R) {
      int r = lrec[idx];
      int slot = atomicAdd(&cur[r & 255], 1);
      srtg[slot] = r;
    }
  }
  __syncthreads();
  // canonical rank-sort within each row -> lrec (deterministic)
#pragma unroll
  for (int j = 0; j < 9; ++j) {
    int idx = j * 512 + t;
    if (idx < R) {
      int r = srtg[idx];
      int node = r & 255;
      int ex = off[node] - hist[node];
      int cnt = hist[node];
      int rank = 0;
      for (int k = ex; k < ex + cnt; ++k) {
        int v = srtg[k];
        rank += (v < r) || (v == r && k < idx);
      }
      lrec[ex + rank] = r >> 8;  // src id
    }
  }
  __syncthreads();
  // write out coalesced
#pragma unroll
  for (int j = 0; j < 9; ++j) {
    int idx = j * 512 + t;
    if (idx < R) recs[rbase + idx] = lrec[idx];
  }
}

// ---------------------------------------------------------------------------
// gather1 (fused combine1): h1 = relu(mean(y1l_nbrs) + b1 + y1r);
//                           z2l = h1@W2l; z2r = h1@W2r
// 16 lanes per node, lane c owns channel c. W2 GEMM via 16-wide shuffles.
// ---------------------------------------------------------------------------
__global__ void __launch_bounds__(256) k_gather1(
    const int* __restrict__ srcSorted, const int* __restrict__ deg,
    const int* __restrict__ rowBeg, const float* __restrict__ y1l,
    const float* __restrict__ y1r, const float* __restrict__ b1,
    const float* __restrict__ W2l, const float* __restrict__ W2r,
    float* __restrict__ z2l, float* __restrict__ z2r) {
  int tid = blockIdx.x * 256 + threadIdx.x;
  int n = tid >> 4;
  int c = tid & 15;
  if (n >= N_NODES) return;
  int beg = rowBeg[n];
  int dg = deg[n];
  int end = beg + dg;
  float acc = 0.f;
  int i = beg;
  for (; i + 4 <= end; i += 4) {
    int s0 = srcSorted[i], s1 = srcSorted[i + 1];
    int s2 = srcSorted[i + 2], s3 = srcSorted[i + 3];
    float a0 = y1l[(size_t)s0 * H + c];
    float a1 = y1l[(size_t)s1 * H + c];
    float a2 = y1l[(size_t)s2 * H + c];
    float a3 = y1l[(size_t)s3 * H + c];
    acc += (a0 + a1) + (a2 + a3);
  }
  for (; i < end; ++i) acc += y1l[(size_t)srcSorted[i] * H + c];
  float inv = 1.f / fmaxf((float)dg, 1.f);
  float h1 = fmaxf(fmaf(acc, inv, b1[c] + y1r[(size_t)n * H + c]), 0.f);
  float zl = 0.f, zr = 0.f;
#pragma unroll
  for (int k = 0; k < H; ++k) {
    float hk = __shfl(h1, k, 16);
    zl = fmaf(hk, W2l[k * H + c], zl);
    zr = fmaf(hk, W2r[k * H + c], zr);
  }
  z2l[(size_t)n * H + c] = zl;
  z2r[(size_t)n * H + c] = zr;
}

// ---------------------------------------------------------------------------
// gather2 (fused combine2): h2 = mean(z2l_nbrs) + b2 + z2r
// ---------------------------------------------------------------------------
__global__ void __launch_bounds__(256) k_gather2(
    const int* __restrict__ srcSorted, const int* __restrict__ deg,
    const int* __restrict__ rowBeg, const float* __restrict__ z2l,
    const float* __restrict__ z2r, const float* __restrict__ b2,
    float* __restrict__ h2) {
  int tid = blockIdx.x * 256 + threadIdx.x;
  int n = tid >> 4;
  int c = tid & 15;
  if (n >= N_NODES) return;
  int beg = rowBeg[n];
  int dg = deg[n];
  int end = beg + dg;
  float acc = 0.f;
  int i = beg;
  for (; i + 4 <= end; i += 4) {
    int s0 = srcSorted[i], s1 = srcSorted[i + 1];
    int s2 = srcSorted[i + 2], s3 = srcSorted[i + 3];
    float a0 = z2l[(size_t)s0 * H + c];
    float a1 = z2l[(size_t)s1 * H + c];
    float a2 = z2l[(size_t)s2 * H + c];
    float a3 = z2l[(size_t)s3 * H + c];
    acc += (a0 + a1) + (a2 + a3);
  }
  for (; i < end; ++i) acc += z2l[(size_t)srcSorted[i] * H + c];
  float inv = 1.f / fmaxf((float)dg, 1.f);
  h2[(size_t)n * H + c] = fmaf(acc, inv, b2[c] + z2r[(size_t)n * H + c]);
}

// ---------------------------------------------------------------------------
// decode: out[p] = sigmoid(dot(h2[s], h2[d]))
// ---------------------------------------------------------------------------
__global__ void __launch_bounds__(256) k_decode(
    const int* __restrict__ ps, const int* __restrict__ pd,
    const float* __restrict__ h2, float* __restrict__ out, int P) {
  int p = blockIdx.x * 256 + threadIdx.x;
  if (p >= P) return;
  int a = ps[p];
  int b = pd[p];
  const float4* ha = (const float4*)(h2 + (size_t)a * H);
  const float4* hb = (const float4*)(h2 + (size_t)b * H);
  float acc = 0.f;
#pragma unroll
  for (int q = 0; q < 4; ++q) {
    float4 u = ha[q];
    float4 v = hb[q];
    acc = fmaf(u.x, v.x, acc);
    acc = fmaf(u.y, v.y, acc);
    acc = fmaf(u.z, v.z, acc);
    acc = fmaf(u.w, v.w, acc);
  }
  out[p] = 1.f / (1.f + __expf(-acc));
}

// ---------------------------------------------------------------------------
extern "C" void kernel_launch(void* const* d_in, const int* in_sizes, int n_in,
                              void* d_out, int out_size, void* d_ws, size_t ws_size,
                              hipStream_t stream) {
  const float* x   = (const float*)d_in[0];
  const float* W1l = (const float*)d_in[1];
  const float* b1  = (const float*)d_in[2];
  const float* W1r = (const float*)d_in[3];
  const float* W2l = (const float*)d_in[4];
  const float* b2  = (const float*)d_in[5];
  const float* W2r = (const float*)d_in[6];
  const int* ei = (const int*)d_in[7];  // [2, E] int32
  const int* di = (const int*)d_in[8];  // [2, P] int32
  const int E = in_sizes[7] / 2;
  const int P = in_sizes[8] / 2;

  const size_t NF = (size_t)N_NODES * H;
  // Aliasing: h2 <- y1l (y1l dead after gather1); z2r <- y1r (gather1 lane
  // for node n reads y1r[n*H+c] then writes z2r[n*H+c], same element, same
  // thread — safe).
  float* y1l = (float*)d_ws;            // NF
  float* y1r = y1l + NF;                // NF
  float* z2l = y1r + NF;                // NF
  float* z2r = y1r;                     // alias
  float* h2  = y1l;                     // alias
  int* recs   = (int*)(z2l + NF);       // NBIN * BINCAP (records -> srcSorted)
  int* binCur = recs + (size_t)NBIN * BINCAP;  // NBIN (padded to 512)
  int* deg    = binCur + 512;           // N
  int* rowBeg = deg + N_NODES;          // N

  const int nodeBlocks = (N_NODES + 255) / 256;
  const int fillBlocks = (E + ECHUNK - 1) / ECHUNK;
  const int gatherBlocks = ((N_NODES * H) + 255) / 256;

  k_init<<<1, 512, 0, stream>>>(binCur);
  k_lin1<<<nodeBlocks, 256, 0, stream>>>(x, W1l, W1r, y1l, y1r);
  k_binfill<<<fillBlocks, 512, 0, stream>>>(ei, ei + E, binCur, recs, E);
  k_binsort<<<NBIN, 512, 0, stream>>>(recs, binCur, deg, rowBeg);
  k_gather1<<<gatherBlocks, 256, 0, stream>>>(recs, deg, rowBeg, y1l, y1r,
                                              b1, W2l, W2r, z2l, z2r);
  k_gather2<<<gatherBlocks, 256, 0, stream>>>(recs, deg, rowBeg, z2l, z2r,
                                              b2, h2);
  k_decode<<<(P + 255) / 256, 256, 0, stream>>>(di, di + P, h2, (float*)d_out, P);
}

// Round 6
// 250.223 us; speedup vs baseline: 2.2390x; 1.1756x over previous
//
#include <hip/hip_runtime.h>
#include <hip/hip_fp16.h>

#define N_NODES 100000
#define F_IN 128
#define H 16
#define NBIN 391           // ceil(N_NODES/256); bin b owns nodes [b*256, b*256+256)
#define BINCAP 4608        // per-bin record capacity (mean 4096, +8 sigma)
#define ECHUNK 4096        // edges per binfill block

// ---------------------------------------------------------------------------
// k_init: binCur[b] = b * BINCAP  (record-region cursors)
// ---------------------------------------------------------------------------
__global__ void __launch_bounds__(512) k_init(int* __restrict__ binCur) {
  int t = threadIdx.x;
  if (t < NBIN) binCur[t] = t * BINCAP;
}

// ---------------------------------------------------------------------------
// k_lin1: y1l = fp16(x @ W1l), y1r = x @ W1r (fp32).  Thread per node.
// y1l is the gather table for layer 1 -> fp16 row = 32 B, table = 3.2 MB
// (fits per-XCD 4 MB L2). y1r is read coalesced once -> keep fp32.
// ---------------------------------------------------------------------------
__global__ void __launch_bounds__(256) k_lin1(
    const float* __restrict__ x, const float* __restrict__ W1l,
    const float* __restrict__ W1r, __half* __restrict__ y1l,
    float* __restrict__ y1r) {
  int n = blockIdx.x * 256 + threadIdx.x;
  if (n >= N_NODES) return;
  const float4* xr = (const float4*)(x + (size_t)n * F_IN);
  float al[H], ar[H];
#pragma unroll
  for (int c = 0; c < H; ++c) { al[c] = 0.f; ar[c] = 0.f; }
  float4 xv = xr[0];
  for (int k4 = 0; k4 < F_IN / 4; ++k4) {
    float4 cur = xv;
    if (k4 + 1 < F_IN / 4) xv = xr[k4 + 1];
    float xs[4] = {cur.x, cur.y, cur.z, cur.w};
#pragma unroll
    for (int j = 0; j < 4; ++j) {
      int k = k4 * 4 + j;
#pragma unroll
      for (int c = 0; c < H; ++c) {
        al[c] = fmaf(xs[j], W1l[k * H + c], al[c]);
        ar[c] = fmaf(xs[j], W1r[k * H + c], ar[c]);
      }
    }
  }
  __half2 hp[8];
#pragma unroll
  for (int q = 0; q < 8; ++q) hp[q] = __floats2half2_rn(al[2 * q], al[2 * q + 1]);
  uint4* ol = (uint4*)(y1l + (size_t)n * H);   // 32 B row = 2x uint4
  ol[0] = *(uint4*)&hp[0];
  ol[1] = *(uint4*)&hp[4];
  float4* orr = (float4*)(y1r + (size_t)n * H);
#pragma unroll
  for (int q = 0; q < 4; ++q)
    orr[q] = make_float4(ar[4 * q], ar[4 * q + 1], ar[4 * q + 2], ar[4 * q + 3]);
}

// ---------------------------------------------------------------------------
// k_binfill: radix pass 1 — bin records (src<<8 | dstLow) by dst>>8.
// Per-block LDS histogram, one global cursor atomicAdd per (block,bin),
// then ranged (sequential) writes: ~2 writers per 64B line, low write amp.
// Record ORDER in a bin is nondeterministic (atomic races) but the record
// SET is deterministic; k_binsort canonicalizes the order.
// ---------------------------------------------------------------------------
__global__ void __launch_bounds__(512) k_binfill(
    const int* __restrict__ src, const int* __restrict__ dst,
    int* __restrict__ binCur, int* __restrict__ recs, int E) {
  __shared__ int hist[512];
  __shared__ int gbase[512];
  __shared__ int cnt2[512];
  int t = threadIdx.x;
  hist[t] = 0;
  cnt2[t] = 0;
  __syncthreads();
  int base = blockIdx.x * ECHUNK;
  int rec[8], bin[8];
#pragma unroll
  for (int j = 0; j < 8; ++j) {
    int e = base + j * 512 + t;
    if (e < E) {
      int s = src[e];
      int d = dst[e];
      rec[j] = (s << 8) | (d & 255);
      bin[j] = d >> 8;
      atomicAdd(&hist[bin[j]], 1);
    } else {
      bin[j] = -1;
    }
  }
  __syncthreads();
  if (t < NBIN) {
    int c = hist[t];
    gbase[t] = (c > 0) ? atomicAdd(&binCur[t], c) : 0;
  }
  __syncthreads();
#pragma unroll
  for (int j = 0; j < 8; ++j) {
    if (bin[j] >= 0) {
      int loc = atomicAdd(&cnt2[bin[j]], 1);
      int slot = gbase[bin[j]] + loc;
      if (slot < (bin[j] + 1) * BINCAP)  // safety clamp (never expected)
        recs[slot] = rec[j];
    }
  }
}

// ---------------------------------------------------------------------------
// k_binsort: radix pass 2 — one block per bin. Canonical rank-sort within
// each row makes the CSR (and thus all fp summation orders) bitwise
// deterministic run-to-run.
// ---------------------------------------------------------------------------
__global__ void __launch_bounds__(512) k_binsort(
    int* __restrict__ recs, const int* __restrict__ binCur,
    int* __restrict__ deg, int* __restrict__ rowBeg) {
  __shared__ int lrec[BINCAP];
  __shared__ int srtg[BINCAP];
  __shared__ int hist[256];
  __shared__ int off[256];       // inclusive scan; (off - hist) = exclusive
  __shared__ int cur[256];
  int t = threadIdx.x;
  int b = blockIdx.x;
  int rbase = b * BINCAP;
  int R = binCur[b] - rbase;
  if (R > BINCAP) R = BINCAP;
  if (t < 256) hist[t] = 0;
  __syncthreads();
#pragma unroll
  for (int j = 0; j < 9; ++j) {
    int idx = j * 512 + t;
    if (idx < R) {
      int r = recs[rbase + idx];
      lrec[idx] = r;
      atomicAdd(&hist[r & 255], 1);
    }
  }
  __syncthreads();
  if (t < 256) off[t] = hist[t];
  __syncthreads();
  for (int o = 1; o < 256; o <<= 1) {
    int u = 0;
    if (t < 256 && t >= o) u = off[t - o];
    __syncthreads();
    if (t < 256) off[t] += u;
    __syncthreads();
  }
  if (t < 256) {
    int ex = off[t] - hist[t];
    cur[t] = ex;
    int n = (b << 8) + t;
    if (n < N_NODES) {
      deg[n] = hist[t];
      rowBeg[n] = rbase + ex;
    }
  }
  __syncthreads();
#pragma unroll
  for (int j = 0; j < 9; ++j) {
    int idx = j * 512 + t;
    if (idx < R) {
      int r = lrec[idx];
      int slot = atomicAdd(&cur[r & 255], 1);
      srtg[slot] = r;
    }
  }
  __syncthreads();
#pragma unroll
  for (int j = 0; j < 9; ++j) {
    int idx = j * 512 + t;
    if (idx < R) {
      int r = srtg[idx];
      int node = r & 255;
      int ex = off[node] - hist[node];
      int cnt = hist[node];
      int rank = 0;
      for (int k = ex; k < ex + cnt; ++k) {
        int v = srtg[k];
        rank += (v < r) || (v == r && k < idx);
      }
      lrec[ex + rank] = r >> 8;  // src id
    }
  }
  __syncthreads();
#pragma unroll
  for (int j = 0; j < 9; ++j) {
    int idx = j * 512 + t;
    if (idx < R) recs[rbase + idx] = lrec[idx];
  }
}

// ---------------------------------------------------------------------------
// gather1 (fused combine1): h1 = relu(mean(y1l_nbrs) + b1 + y1r);
//                           z2l = fp16(h1@W2l); z2r = h1@W2r (fp32)
// 16 lanes per node, lane c owns channel c. W2 GEMM via 16-wide shuffles.
// ---------------------------------------------------------------------------
__global__ void __launch_bounds__(256) k_gather1(
    const int* __restrict__ srcSorted, const int* __restrict__ deg,
    const int* __restrict__ rowBeg, const __half* __restrict__ y1l,
    const float* __restrict__ y1r, const float* __restrict__ b1,
    const float* __restrict__ W2l, const float* __restrict__ W2r,
    __half* __restrict__ z2l, float* __restrict__ z2r) {
  int tid = blockIdx.x * 256 + threadIdx.x;
  int n = tid >> 4;
  int c = tid & 15;
  if (n >= N_NODES) return;
  int beg = rowBeg[n];
  int dg = deg[n];
  int end = beg + dg;
  float acc = 0.f;
  int i = beg;
  for (; i + 4 <= end; i += 4) {
    int s0 = srcSorted[i], s1 = srcSorted[i + 1];
    int s2 = srcSorted[i + 2], s3 = srcSorted[i + 3];
    float a0 = __half2float(y1l[(size_t)s0 * H + c]);
    float a1 = __half2float(y1l[(size_t)s1 * H + c]);
    float a2 = __half2float(y1l[(size_t)s2 * H + c]);
    float a3 = __half2float(y1l[(size_t)s3 * H + c]);
    acc += (a0 + a1) + (a2 + a3);
  }
  for (; i < end; ++i) acc += __half2float(y1l[(size_t)srcSorted[i] * H + c]);
  float inv = 1.f / fmaxf((float)dg, 1.f);
  float h1 = fmaxf(fmaf(acc, inv, b1[c] + y1r[(size_t)n * H + c]), 0.f);
  float zl = 0.f, zr = 0.f;
#pragma unroll
  for (int k = 0; k < H; ++k) {
    float hk = __shfl(h1, k, 16);
    zl = fmaf(hk, W2l[k * H + c], zl);
    zr = fmaf(hk, W2r[k * H + c], zr);
  }
  z2l[(size_t)n * H + c] = __float2half_rn(zl);
  z2r[(size_t)n * H + c] = zr;
}

// ---------------------------------------------------------------------------
// gather2 (fused combine2): h2 = fp16(mean(z2l_nbrs) + b2 + z2r)
// ---------------------------------------------------------------------------
__global__ void __launch_bounds__(256) k_gather2(
    const int* __restrict__ srcSorted, const int* __restrict__ deg,
    const int* __restrict__ rowBeg, const __half* __restrict__ z2l,
    const float* __restrict__ z2r, const float* __restrict__ b2,
    __half* __restrict__ h2) {
  int tid = blockIdx.x * 256 + threadIdx.x;
  int n = tid >> 4;
  int c = tid & 15;
  if (n >= N_NODES) return;
  int beg = rowBeg[n];
  int dg = deg[n];
  int end = beg + dg;
  float acc = 0.f;
  int i = beg;
  for (; i + 4 <= end; i += 4) {
    int s0 = srcSorted[i], s1 = srcSorted[i + 1];
    int s2 = srcSorted[i + 2], s3 = srcSorted[i + 3];
    float a0 = __half2float(z2l[(size_t)s0 * H + c]);
    float a1 = __half2float(z2l[(size_t)s1 * H + c]);
    float a2 = __half2float(z2l[(size_t)s2 * H + c]);
    float a3 = __half2float(z2l[(size_t)s3 * H + c]);
    acc += (a0 + a1) + (a2 + a3);
  }
  for (; i < end; ++i) acc += __half2float(z2l[(size_t)srcSorted[i] * H + c]);
  float inv = 1.f / fmaxf((float)dg, 1.f);
  float v = fmaf(acc, inv, b2[c] + z2r[(size_t)n * H + c]);
  h2[(size_t)n * H + c] = __float2half_rn(v);
}

// ---------------------------------------------------------------------------
// decode: out[p] = sigmoid(dot(h2[s], h2[d]))  — h2 rows are 32 B fp16
// ---------------------------------------------------------------------------
__device__ inline float dot8h(uint4 u, uint4 v) {
  float acc = 0.f;
  const unsigned int* uw = (const unsigned int*)&u;
  const unsigned int* vw = (const unsigned int*)&v;
#pragma unroll
  for (int j = 0; j < 4; ++j) {
    float2 a = __half22float2(*(const __half2*)&uw[j]);
    float2 b = __half22float2(*(const __half2*)&vw[j]);
    acc = fmaf(a.x, b.x, acc);
    acc = fmaf(a.y, b.y, acc);
  }
  return acc;
}

__global__ void __launch_bounds__(256) k_decode(
    const int* __restrict__ ps, const int* __restrict__ pd,
    const __half* __restrict__ h2, float* __restrict__ out, int P) {
  int p = blockIdx.x * 256 + threadIdx.x;
  if (p >= P) return;
  int a = ps[p];
  int b = pd[p];
  const uint4* ha = (const uint4*)(h2 + (size_t)a * H);  // 2x16B per row
  const uint4* hb = (const uint4*)(h2 + (size_t)b * H);
  uint4 u0 = ha[0], u1 = ha[1];
  uint4 v0 = hb[0], v1 = hb[1];
  float acc = dot8h(u0, v0) + dot8h(u1, v1);
  out[p] = 1.f / (1.f + __expf(-acc));
}

// ---------------------------------------------------------------------------
extern "C" void kernel_launch(void* const* d_in, const int* in_sizes, int n_in,
                              void* d_out, int out_size, void* d_ws, size_t ws_size,
                              hipStream_t stream) {
  const float* x   = (const float*)d_in[0];
  const float* W1l = (const float*)d_in[1];
  const float* b1  = (const float*)d_in[2];
  const float* W1r = (const float*)d_in[3];
  const float* W2l = (const float*)d_in[4];
  const float* b2  = (const float*)d_in[5];
  const float* W2r = (const float*)d_in[6];
  const int* ei = (const int*)d_in[7];  // [2, E] int32
  const int* di = (const int*)d_in[8];  // [2, P] int32
  const int E = in_sizes[7] / 2;
  const int P = in_sizes[8] / 2;

  const size_t NF = (size_t)N_NODES * H;
  // fp16 tables (gathered randomly; 3.2 MB each, L2-resident):
  //   y1l -> aliased as h2 after gather1 retires y1l; z2l separate.
  // fp32 per-node streams: y1r -> aliased as z2r (same thread+element).
  __half* y1l = (__half*)d_ws;          // NF halves
  __half* h2  = y1l;                    // alias (y1l dead after gather1)
  __half* z2l = y1l + NF;               // NF halves
  float*  y1r = (float*)(z2l + NF);     // NF floats
  float*  z2r = y1r;                    // alias
  int* recs   = (int*)(y1r + NF);       // NBIN * BINCAP (records -> srcSorted)
  int* binCur = recs + (size_t)NBIN * BINCAP;  // NBIN (padded to 512)
  int* deg    = binCur + 512;           // N
  int* rowBeg = deg + N_NODES;          // N

  const int nodeBlocks = (N_NODES + 255) / 256;
  const int fillBlocks = (E + ECHUNK - 1) / ECHUNK;
  const int gatherBlocks = ((N_NODES * H) + 255) / 256;

  k_init<<<1, 512, 0, stream>>>(binCur);
  k_lin1<<<nodeBlocks, 256, 0, stream>>>(x, W1l, W1r, y1l, y1r);
  k_binfill<<<fillBlocks, 512, 0, stream>>>(ei, ei + E, binCur, recs, E);
  k_binsort<<<NBIN, 512, 0, stream>>>(recs, binCur, deg, rowBeg);
  k_gather1<<<gatherBlocks, 256, 0, stream>>>(recs, deg, rowBeg, y1l, y1r,
                                              b1, W2l, W2r, z2l, z2r);
  k_gather2<<<gatherBlocks, 256, 0, stream>>>(recs, deg, rowBeg, z2l, z2r,
                                              b2, h2);
  k_decode<<<(P + 255) / 256, 256, 0, stream>>>(di, di + P, h2, (float*)d_out, P);
}